// Round 3
// baseline (927.404 us; speedup 1.0000x reference)
//
#include <hip/hip_runtime.h>
#include <hip/hip_bf16.h>

#define NN 768
#define NE 24576
#define NPOS 4096
#define NCELL (NN*NN)   // 589824

typedef __hip_bfloat16 bf16;

__device__ __forceinline__ float bf2f(bf16 v) { return __bfloat162float(v); }

// dtype-flexible load: mode==1 -> bf16 storage, mode==0 -> f32 storage
__device__ __forceinline__ float ldf(const void* p, int i, int mode) {
    return mode ? __bfloat162float(((const bf16*)p)[i]) : ((const float*)p)[i];
}

// ---------------- detect float storage dtype from emb ----------------
// bf16-stored 0.1*N(0,1): all |v| < ~1. f32-stored read as bf16: low halves
// are mantissa bits -> random exponents -> some |v| huge (or NaN).
__global__ void k_detect(const void* __restrict__ emb, int* __restrict__ mode) {
    __shared__ int bad;
    if (threadIdx.x == 0) bad = 0;
    __syncthreads();
    int t = threadIdx.x;
    int local = 0;
    for (int i = t; i < 3232; i += 256) {
        float v = __bfloat162float(((const bf16*)emb)[i]);
        float a = fabsf(v);
        if (!(a < 100.f)) local = 1;   // also catches NaN/Inf
    }
    if (local) atomicOr(&bad, 1);
    __syncthreads();
    if (t == 0) *mode = bad ? 0 : 1;   // 1 = bf16, 0 = f32
}

// ---------------- init: cell=0 (counts phase), stats=0 ----------------
__global__ void k_init(int* __restrict__ cell, float* __restrict__ stats) {
    int idx = blockIdx.x * 256 + threadIdx.x;
    if (idx < NCELL) cell[idx] = 0;
    if (idx < 66) stats[idx] = 0.f;
}

// ---------------- convert weights -> f32 (W3 transposed, stride 33) ----------------
__global__ void k_conv(const void* __restrict__ gW, const void* __restrict__ gB,
                       const void* __restrict__ m1W, const void* __restrict__ m1B,
                       const void* __restrict__ m2W, const void* __restrict__ m2B,
                       const void* __restrict__ m3W, const void* __restrict__ m3B,
                       const void* __restrict__ lW,  const void* __restrict__ lB,
                       const int* __restrict__ modep,
                       float* __restrict__ gwf, float* __restrict__ gbf,
                       float* __restrict__ w1f, float* __restrict__ b1f,
                       float* __restrict__ w2f, float* __restrict__ b2f,
                       float* __restrict__ w3t, float* __restrict__ b3f,
                       float* __restrict__ linf, float* __restrict__ linb) {
    int t = threadIdx.x;
    int mode = *modep;
    for (int i = t; i < 2048; i += 256) {
        gwf[i] = ldf(gW, i, mode);
        w1f[i] = ldf(m1W, i, mode);
        w2f[i] = ldf(m2W, i, mode);
    }
    for (int i = t; i < 64; i += 256) { gbf[i] = ldf(gB, i, mode); linf[i] = ldf(lW, i, mode); }
    if (t < 32) { b1f[t] = ldf(m1B, t, mode); b2f[t] = ldf(m2B, t, mode); b3f[t] = ldf(m3B, t, mode); }
    // m3W is (33,32) row-major; w3t[d*33+c] = W3[c][d]
    for (int i = t; i < 1056; i += 256) { int c = i >> 5, d = i & 31; w3t[d * 33 + c] = ldf(m3W, i, mode); }
    if (t == 0) linb[0] = ldf(lB, 0, mode);
}

// ---------------- edge scatter: per-cell edge multiplicity ----------------
__global__ void k_scatter(const int* __restrict__ ei, int* __restrict__ cell) {
    int e = blockIdx.x * 256 + threadIdx.x;
    if (e < NE) {
        int a = ei[e], b = ei[NE + e];
        if ((unsigned)a < (unsigned)NN && (unsigned)b < (unsigned)NN)
            atomicAdd(&cell[a * NN + b], 1);
    }
}

// ---------------- per-row nnz + dinv (one wave per row, shfl reduce) ----------------
__global__ void k_rowcount(const int* __restrict__ cell, int* __restrict__ rowlen, float* __restrict__ dinv) {
    int lane = threadIdx.x & 63;
    int i = (blockIdx.x * 256 + threadIdx.x) >> 6;
    if (i >= NN) return;
    int rl = 0;
    for (int c = 0; c < 12; c++) rl += (cell[i * NN + c * 64 + lane] > 0) ? 1 : 0;
    for (int off = 32; off >= 1; off >>= 1) rl += __shfl_xor(rl, off);
    if (lane == 0) { rowlen[i] = rl; dinv[i] = rsqrtf((float)rl + 1.0f); }  // Ahat row sum = rl + 1
}

// ---------------- exclusive scan (LDS-staged, serial on thread 0) ----------------
__global__ void k_scan(const int* __restrict__ rowlen, int* __restrict__ row_ptr) {
    __shared__ int s[NN];
    __shared__ int ps[NN + 1];
    int t = threadIdx.x;
    for (int i = t; i < NN; i += 256) s[i] = rowlen[i];
    __syncthreads();
    if (t == 0) {
        int a = 0;
        for (int i = 0; i < NN; i++) { ps[i] = a; a += s[i]; }
        ps[NN] = a;
    }
    __syncthreads();
    for (int i = t; i <= NN; i += 256) row_ptr[i] = ps[i];
}

// ---------------- CSR fill, one thread per row; cell becomes pairIdx in-place ----------------
__global__ void k_fill(int* __restrict__ cell, const int* __restrict__ row_ptr,
                       int* __restrict__ col_idx, float* __restrict__ cntv, int* __restrict__ pr_row) {
    int i = blockIdx.x * 256 + threadIdx.x;
    if (i >= NN) return;
    int p = row_ptr[i];
    for (int j = 0; j < NN; j++) {
        int cv = cell[i * NN + j];
        if (cv > 0) {
            col_idx[p] = j; cntv[p] = (float)cv; pr_row[p] = i;
            cell[i * NN + j] = p;
            p++;
        } else {
            cell[i * NN + j] = -1;
        }
    }
}

// ---------------- embedding gather ----------------
__global__ void k_emb(const int* __restrict__ x, const void* __restrict__ emb,
                      const int* __restrict__ modep, float* __restrict__ h) {
    int idx = blockIdx.x * 256 + threadIdx.x;  // < 24576
    int i = idx >> 5, d = idx & 31;
    int xi = x[i];
    if (xi < 0) xi = 0; if (xi > 100) xi = 100;
    h[idx] = ldf(emb, xi * 32 + d, *modep);
}

// ---------------- h @ W ----------------
__global__ void k_matw(const float* __restrict__ h, const float* __restrict__ gwf, int l, float* __restrict__ o) {
    int idx = blockIdx.x * 256 + threadIdx.x;
    int i = idx >> 5, d = idx & 31;
    const float* W = gwf + l * 1024;
    float s = 0.f;
#pragma unroll
    for (int c = 0; c < 32; c++) s += h[i * 32 + c] * W[c * 32 + d];
    o[idx] = s;
}

// ---------------- An @ hw + b (sparse; eye term separate) ----------------
__global__ void k_agg(const float* __restrict__ hw, const int* __restrict__ row_ptr,
                      const int* __restrict__ col_idx, const float* __restrict__ dinv,
                      const float* __restrict__ gbf, int l, float* __restrict__ o) {
    int idx = blockIdx.x * 256 + threadIdx.x;
    int i = idx >> 5, d = idx & 31;
    int base = row_ptr[i], len = row_ptr[i + 1] - base;
    if (len < 0) len = 0; if (len > NN) len = NN;
    float di = dinv[i];
    float acc = di * hw[i * 32 + d];  // eye term of Ahat
    for (int t = 0; t < len; t++) {
        int c = col_idx[base + t];
        if ((unsigned)c < (unsigned)NN) acc += dinv[c] * hw[c * 32 + d];
    }
    o[idx] = di * acc + gbf[l * 32 + d];
}

// ---------------- graph norm + relu (single block) ----------------
__global__ void k_norm(const float* __restrict__ in, float* __restrict__ out) {
    __shared__ float red[256];
    __shared__ float mean[32], rstd[32];
    int t = threadIdx.x, d = t & 31, g = t >> 5;
    float p = 0.f;
    for (int r = g; r < NN; r += 8) p += in[r * 32 + d];
    red[t] = p;
    __syncthreads();
    if (t < 32) { float s = 0.f; for (int k = 0; k < 8; k++) s += red[k * 32 + t]; mean[t] = s / (float)NN; }
    __syncthreads();
    p = 0.f;
    for (int r = g; r < NN; r += 8) { float v = in[r * 32 + d] - mean[d]; p += v * v; }
    red[t] = p;
    __syncthreads();
    if (t < 32) { float s = 0.f; for (int k = 0; k < 8; k++) s += red[k * 32 + t]; rstd[t] = rsqrtf(s / (float)NN + 1e-5f); }
    __syncthreads();
    for (int e = t; e < NN * 32; e += 256) {
        int dd = e & 31;
        out[e] = fmaxf((in[e] - mean[dd]) * rstd[dd], 0.f);
    }
}

// ---------------- per-distinct-pair MLP1/MLP2, premultiplied by multiplicity ----------------
__global__ void k_edgemlp(const float* __restrict__ h, const int* __restrict__ row_ptr,
                          const int* __restrict__ col_idx, const int* __restrict__ pr_row,
                          const float* __restrict__ cntv,
                          const float* __restrict__ w1f, const float* __restrict__ b1f,
                          const float* __restrict__ w2f, const float* __restrict__ b2f,
                          float* __restrict__ xep, float* __restrict__ mulp) {
    int t = threadIdx.x, d = t & 31;
    int p = blockIdx.x * 8 + (t >> 5);
    if (p >= NE) return;
    if (p >= row_ptr[NN]) { xep[p * 32 + d] = 0.f; mulp[p * 32 + d] = 0.f; return; }
    int i = pr_row[p], j = col_idx[p];
    if ((unsigned)i >= (unsigned)NN) i = 0;
    if ((unsigned)j >= (unsigned)NN) j = 0;
    float a1 = b1f[d], a2 = b2f[d];
#pragma unroll
    for (int c = 0; c < 32; c++) {
        float hv = h[i * 32 + c];
        a1 += hv * w1f[c * 32 + d];
        a2 += hv * w2f[c * 32 + d];
    }
#pragma unroll
    for (int c = 0; c < 32; c++) {
        float hv = h[j * 32 + c];
        a1 += hv * w1f[(32 + c) * 32 + d];
        a2 += hv * w2f[(32 + c) * 32 + d];
    }
    float cv = cntv[p];
    xep[p * 32 + d]  = cv * fmaxf(a1, 0.f);   // Xd[i,j,:] summed over duplicates
    mulp[p * 32 + d] = cv * fmaxf(a2, 0.f);   // Md[i,j,:]
}

// ---------------- fused: C gather + z + masked stats over all 768x768 cells ----------------
__global__ __launch_bounds__(256) void k_big(const int* __restrict__ row_ptr, const int* __restrict__ col_idx,
                                             const int* __restrict__ cell,
                                             const float* __restrict__ xep, const float* __restrict__ mulp,
                                             const float* __restrict__ w3t, const float* __restrict__ b3f,
                                             float* __restrict__ stats) {
    __shared__ float ws1[4][32], ws2[4][32], wcm[4];
    float s1[32], s2[32];
#pragma unroll
    for (int d = 0; d < 32; d++) { s1[d] = 0.f; s2[d] = 0.f; }
    float cm = 0.f;
    int t = threadIdx.x, lane = t & 63, w = t >> 6;
    int npairs = row_ptr[NN];
    if (npairs < 0) npairs = 0; if (npairs > NE) npairs = NE;
    for (int it = 0; it < 3; it++) {
        int n = it * (NN * 256) + blockIdx.x * 256 + t;  // block spans 256 consecutive j in one row
        int i = n / NN;
        int j = n - i * NN;
        int base = row_ptr[i];
        int len = row_ptr[i + 1] - base;
        if (len < 0) len = 0; if (len > NN) len = NN;
        float acc[32];
#pragma unroll
        for (int d = 0; d < 32; d++) acc[d] = 0.f;
        bool hit = false;
        for (int tt = 0; tt < len; tt++) {
            int e1 = base + tt;
            if ((unsigned)e1 >= (unsigned)npairs) break;
            int k = col_idx[e1];
            if ((unsigned)k >= (unsigned)NN) continue;
            int e2 = cell[k * NN + j];
            if (e2 >= 0 && e2 < npairs) {
                hit = true;
                const float* xr = xep + e1 * 32;
                const float* mr = mulp + e2 * 32;
#pragma unroll
                for (int d = 0; d < 32; d++) acc[d] += xr[d] * mr[d];
            }
        }
        bool adj = cell[i * NN + j] >= 0;
        float af = adj ? 1.f : 0.f;
        float msk = (hit || adj) ? 1.f : 0.f;
        cm += msk;
#pragma unroll
        for (int d = 0; d < 32; d++) {
            const float* wr = w3t + d * 33;   // wave-uniform -> scalar loads
            float z = b3f[d] + af * wr[32];
#pragma unroll
            for (int c = 0; c < 32; c++) z += acc[c] * wr[c];
            s1[d] += msk * z;
            s2[d] += msk * z * z;
        }
    }
#pragma unroll
    for (int d = 0; d < 32; d++) {
        float v = s1[d];
        for (int off = 32; off >= 1; off >>= 1) v += __shfl_xor(v, off);
        if (lane == 0) ws1[w][d] = v;
        float u = s2[d];
        for (int off = 32; off >= 1; off >>= 1) u += __shfl_xor(u, off);
        if (lane == 0) ws2[w][d] = u;
    }
    {
        float v = cm;
        for (int off = 32; off >= 1; off >>= 1) v += __shfl_xor(v, off);
        if (lane == 0) wcm[w] = v;
    }
    __syncthreads();
    if (t < 32) {
        float a = 0.f, b = 0.f;
        for (int k = 0; k < 4; k++) { a += ws1[k][t]; b += ws2[k][t]; }
        atomicAdd(&stats[t], a);
        atomicAdd(&stats[32 + t], b);
    }
    if (t == 0) atomicAdd(&stats[64], wcm[0] + wcm[1] + wcm[2] + wcm[3]);
}

// ---------------- finalize mean / rstd ----------------
__global__ void k_finalize(const float* __restrict__ stats, float* __restrict__ nrm) {
    int t = threadIdx.x;
    if (t < 32) {
        float cmv = stats[64];
        if (cmv < 1.f) cmv = 1.f;
        float mean = stats[t] / cmv;
        float var = stats[32 + t] / cmv - mean * mean;
        nrm[t] = mean;
        nrm[32 + t] = rsqrtf(fmaxf(var, 0.f) + 1e-5f);
    }
}

// ---------------- output: recompute C at pos pairs (both directions), norm, sym, linear ----------------
__global__ void k_out(const int* __restrict__ pos, const int* __restrict__ row_ptr,
                      const int* __restrict__ col_idx, const int* __restrict__ cell,
                      const float* __restrict__ xep, const float* __restrict__ mulp,
                      const float* __restrict__ h,
                      const float* __restrict__ w3t, const float* __restrict__ b3f,
                      const float* __restrict__ nrm,
                      const float* __restrict__ linf, const float* __restrict__ linb,
                      const int* __restrict__ modep, void* __restrict__ outp) {
    __shared__ float Cb[4][2][32];
    int t = threadIdx.x;
    int w = t >> 6, lane = t & 63, d = lane & 31, dir = lane >> 5;
    int p = blockIdx.x * 4 + w;
    int a = pos[2 * p], b = pos[2 * p + 1];
    if ((unsigned)a >= (unsigned)NN) a = 0;
    if ((unsigned)b >= (unsigned)NN) b = 0;
    int r = dir ? b : a;
    int cc = dir ? a : b;
    int npairs = row_ptr[NN];
    if (npairs < 0) npairs = 0; if (npairs > NE) npairs = NE;
    int base = row_ptr[r], len = row_ptr[r + 1] - base;
    if (len < 0) len = 0; if (len > NN) len = NN;
    float acc = 0.f;
    bool hit = false;
    for (int tt = 0; tt < len; tt++) {
        int e1 = base + tt;
        if ((unsigned)e1 >= (unsigned)npairs) break;
        int k = col_idx[e1];
        if ((unsigned)k >= (unsigned)NN) continue;
        int e2 = cell[k * NN + cc];
        if (e2 >= 0 && e2 < npairs) { hit = true; acc += xep[e1 * 32 + d] * mulp[e2 * 32 + d]; }
    }
    Cb[w][dir][d] = acc;
    bool adj = cell[r * NN + cc] >= 0;
    float msk = (hit || adj) ? 1.f : 0.f;
    __syncthreads();
    float z = b3f[d] + (adj ? 1.f : 0.f) * w3t[d * 33 + 32];
#pragma unroll
    for (int c = 0; c < 32; c++) z += Cb[w][dir][c] * w3t[d * 33 + c];
    float zn = fmaxf((z - nrm[d]) * nrm[32 + d], 0.f);
    float zp = __shfl_xor(zn, 32);                 // partner direction's zn
    float symd = msk * zn * zp;                    // sym[r,cc,d]
    float xxd = h[a * 32 + d] * h[b * 32 + d];
    float contrib = symd * linf[d] + xxd * linf[32 + d];
    for (int off = 16; off >= 1; off >>= 1) contrib += __shfl_xor(contrib, off);
    if (lane == 0) {
        float v = contrib + linb[0];
        // canary clamp: correct values are |v| <= ~180; 1e4 only trips on garbage
        v = fminf(fmaxf(v, -1e4f), 1e4f);
        if (*modep) ((bf16*)outp)[p] = __float2bfloat16(v);
        else        ((float*)outp)[p] = v;
    }
}

extern "C" void kernel_launch(void* const* d_in, const int* in_sizes, int n_in,
                              void* d_out, int out_size, void* d_ws, size_t ws_size,
                              hipStream_t stream) {
    // Default: setup_inputs() dict order
    const void* px  = d_in[0];  const void* pei = d_in[1];  const void* ppos = d_in[2];
    const void* pemb = d_in[3]; const void* pgW = d_in[4];  const void* pgB  = d_in[5];
    const void* pm1W = d_in[6]; const void* pm1B = d_in[7]; const void* pm2W = d_in[8];
    const void* pm2B = d_in[9]; const void* pm3W = d_in[10]; const void* pm3B = d_in[11];
    const void* plW = d_in[12]; const void* plB = d_in[13];
    // Size-based resolution (identity under dict order; robust to reordering).
    {
        int c2048 = 0, c64 = 0, c32 = 0;
        for (int i = 0; i < n_in; i++) {
            int s = in_sizes[i]; const void* p = d_in[i];
            switch (s) {
                case 768:   px = p; break;
                case 49152: pei = p; break;
                case 8192:  ppos = p; break;
                case 3232:  pemb = p; break;
                case 2048:  if (c2048 == 0) pgW = p; else if (c2048 == 1) pm1W = p; else pm2W = p; c2048++; break;
                case 64:    if (c64 == 0) pgB = p; else plW = p; c64++; break;
                case 32:    if (c32 == 0) pm1B = p; else if (c32 == 1) pm2B = p; else pm3B = p; c32++; break;
                case 1056:  pm3W = p; break;
                case 1:     plB = p; break;
                default: break;
            }
        }
    }

    char* ws = (char*)d_ws;
    size_t off = 0;
    auto alloc = [&](size_t bytes) -> void* {
        void* pp = ws + off;
        off += (bytes + 255) & ~(size_t)255;
        return pp;
    };
    int*   cell    = (int*)alloc(NCELL * 4);       // counts, then pairIdx in-place
    int*   rowlen  = (int*)alloc(NN * 4);
    int*   row_ptr = (int*)alloc((NN + 1) * 4);
    int*   col_idx = (int*)alloc(NE * 4);
    float* cntv    = (float*)alloc(NE * 4);
    int*   pr_row  = (int*)alloc(NE * 4);
    float* dinv    = (float*)alloc(NN * 4);
    float* h       = (float*)alloc(NN * 32 * 4);
    float* bufA    = (float*)alloc(NN * 32 * 4);
    float* bufB    = (float*)alloc(NN * 32 * 4);
    float* xep     = (float*)alloc(NE * 32 * 4);
    float* mulp    = (float*)alloc(NE * 32 * 4);
    float* stats   = (float*)alloc(66 * 4);
    float* nrm     = (float*)alloc(64 * 4);
    float* gwf     = (float*)alloc(2048 * 4);
    float* gbf     = (float*)alloc(64 * 4);
    float* w1f     = (float*)alloc(2048 * 4);
    float* b1f     = (float*)alloc(32 * 4);
    float* w2f     = (float*)alloc(2048 * 4);
    float* b2f     = (float*)alloc(32 * 4);
    float* w3t     = (float*)alloc(1056 * 4);
    float* b3f     = (float*)alloc(32 * 4);
    float* linf    = (float*)alloc(64 * 4);
    float* linb    = (float*)alloc(4);
    int*   mode    = (int*)alloc(4);

    k_detect<<<1, 256, 0, stream>>>(pemb, mode);
    k_init<<<NCELL / 256, 256, 0, stream>>>(cell, stats);
    k_conv<<<1, 256, 0, stream>>>(pgW, pgB, pm1W, pm1B, pm2W, pm2B, pm3W, pm3B, plW, plB, mode,
                                  gwf, gbf, w1f, b1f, w2f, b2f, w3t, b3f, linf, linb);
    k_scatter<<<NE / 256, 256, 0, stream>>>((const int*)pei, cell);
    k_rowcount<<<NN / 4, 256, 0, stream>>>(cell, rowlen, dinv);
    k_scan<<<1, 256, 0, stream>>>(rowlen, row_ptr);
    k_fill<<<3, 256, 0, stream>>>(cell, row_ptr, col_idx, cntv, pr_row);
    k_emb<<<NN * 32 / 256, 256, 0, stream>>>((const int*)px, pemb, mode, h);
    for (int l = 0; l < 2; l++) {
        k_matw<<<NN * 32 / 256, 256, 0, stream>>>(h, gwf, l, bufA);
        k_agg<<<NN * 32 / 256, 256, 0, stream>>>(bufA, row_ptr, col_idx, dinv, gbf, l, bufB);
        k_norm<<<1, 256, 0, stream>>>(bufB, h);
    }
    k_edgemlp<<<NE / 8, 256, 0, stream>>>(h, row_ptr, col_idx, pr_row, cntv, w1f, b1f, w2f, b2f, xep, mulp);
    k_big<<<NN, 256, 0, stream>>>(row_ptr, col_idx, cell, xep, mulp, w3t, b3f, stats);
    k_finalize<<<1, 64, 0, stream>>>(stats, nrm);
    k_out<<<NPOS / 4, 256, 0, stream>>>((const int*)ppos, row_ptr, col_idx, cell, xep, mulp, h,
                                        w3t, b3f, nrm, linf, linb, mode, d_out);
}

// Round 4
// 453.087 us; speedup vs baseline: 2.0469x; 2.0469x over previous
//
#include <hip/hip_runtime.h>
#include <hip/hip_bf16.h>

#define NN 768
#define NE 24576
#define NPOS 4096
#define NCELL (NN*NN)   // 589824 = 2304*256
#define GRID_BIG 2304

typedef __hip_bfloat16 bf16;

__device__ __forceinline__ float bf2f(bf16 v) { return __bfloat162float(v); }

// dtype-flexible load: mode==1 -> bf16 storage, mode==0 -> f32 storage
__device__ __forceinline__ float ldf(const void* p, int i, int mode) {
    return mode ? __bfloat162float(((const bf16*)p)[i]) : ((const float*)p)[i];
}

// ---------------- setup: clear cell/aux, detect dtype, convert weights ----------------
// blocks 0..2303: clear cell. block 2304: detect + conv. block 2305: clear aux.
__global__ void k_setup(const void* __restrict__ gW, const void* __restrict__ gB,
                        const void* __restrict__ m1W, const void* __restrict__ m1B,
                        const void* __restrict__ m2W, const void* __restrict__ m2B,
                        const void* __restrict__ m3W, const void* __restrict__ m3B,
                        const void* __restrict__ lW,  const void* __restrict__ lB,
                        const void* __restrict__ emb,
                        int* __restrict__ cell, float* __restrict__ stats,
                        int* __restrict__ cursor, int* __restrict__ rowlen, int* __restrict__ done,
                        int* __restrict__ modeg,
                        float* __restrict__ gwf, float* __restrict__ gbf,
                        float* __restrict__ w1f, float* __restrict__ b1f,
                        float* __restrict__ w2f, float* __restrict__ b2f,
                        float* __restrict__ w3q, float* __restrict__ linf, float* __restrict__ linb) {
    int t = threadIdx.x;
    int b = blockIdx.x;
    if (b < GRID_BIG) {
        cell[b * 256 + t] = 0;
        return;
    }
    if (b == GRID_BIG + 1) {
        for (int i = t; i < 768; i += 256) { cursor[i] = 0; rowlen[i] = 0; }
        if (t < 66) stats[t] = 0.f;
        if (t == 0) *done = 0;
        return;
    }
    // block 2304: detect dtype then convert weights
    __shared__ int bad;
    if (t == 0) bad = 0;
    __syncthreads();
    int local = 0;
    for (int i = t; i < 3232; i += 256) {
        float a = fabsf(__bfloat162float(((const bf16*)emb)[i]));
        if (!(a < 100.f)) local = 1;   // catches huge / NaN / Inf
    }
    if (local) atomicOr(&bad, 1);
    __syncthreads();
    int mode = bad ? 0 : 1;           // 1 = bf16 storage, 0 = f32
    if (t == 0) *modeg = mode;
    for (int i = t; i < 2048; i += 256) {
        gwf[i] = ldf(gW, i, mode);
        w1f[i] = ldf(m1W, i, mode);
        w2f[i] = ldf(m2W, i, mode);
    }
    for (int i = t; i < 64; i += 256) { gbf[i] = ldf(gB, i, mode); linf[i] = ldf(lW, i, mode); }
    if (t < 32) { b1f[t] = ldf(m1B, t, mode); b2f[t] = ldf(m2B, t, mode); }
    // w3q row d (stride 36): [ W3[0..31][d], W3[32][d] (ind), b3[d], 0, 0 ]
    for (int i = t; i < 1056; i += 256) { int c = i >> 5, d = i & 31; w3q[d * 36 + c] = ldf(m3W, i, mode); }
    if (t < 32) { w3q[t * 36 + 33] = ldf(m3B, t, mode); w3q[t * 36 + 34] = 0.f; w3q[t * 36 + 35] = 0.f; }
    if (t == 0) linb[0] = ldf(lB, 0, mode);
}

// ---------------- edge scatter + first-touch rowlen ----------------
__global__ void k_scatter(const int* __restrict__ ei, int* __restrict__ cell, int* __restrict__ rowlen) {
    int e = blockIdx.x * 256 + threadIdx.x;
    if (e < NE) {
        int a = ei[e], b = ei[NE + e];
        if ((unsigned)a < (unsigned)NN && (unsigned)b < (unsigned)NN) {
            int old = atomicAdd(&cell[a * NN + b], 1);
            if (old == 0) atomicAdd(&rowlen[a], 1);
        }
    }
}

// ---------------- scan (serial thread 0) + dinv ----------------
__global__ void k_scan(const int* __restrict__ rowlen, int* __restrict__ row_ptr, float* __restrict__ dinv) {
    __shared__ int s[NN];
    __shared__ int ps[NN + 1];
    int t = threadIdx.x;
    for (int i = t; i < NN; i += 256) { s[i] = rowlen[i]; dinv[i] = rsqrtf((float)rowlen[i] + 1.0f); }
    __syncthreads();
    if (t == 0) {
        int a = 0;
        for (int i = 0; i < NN; i++) { ps[i] = a; a += s[i]; }
        ps[NN] = a;
    }
    __syncthreads();
    for (int i = t; i <= NN; i += 256) row_ptr[i] = ps[i];
}

// ---------------- parallel CSR fill (order-free within row); cell -> pairIdx in-place ----------------
__global__ void k_fillpar(int* __restrict__ cell, const int* __restrict__ row_ptr, int* __restrict__ cursor,
                          int* __restrict__ col_idx, float* __restrict__ cntv, int* __restrict__ pr_row) {
    int idx = blockIdx.x * 256 + threadIdx.x;
    if (idx >= NCELL) return;
    int i = idx / NN;
    int j = idx - i * NN;
    int cv = cell[idx];
    if (cv > 0) {
        int p = row_ptr[i] + atomicAdd(&cursor[i], 1);
        col_idx[p] = j; cntv[p] = (float)cv; pr_row[p] = i;
        cell[idx] = p;
    } else {
        cell[idx] = -1;
    }
}

// ---------------- layer-0: fused emb gather + h @ W0 ----------------
__global__ void k_matw0(const int* __restrict__ x, const void* __restrict__ emb,
                        const int* __restrict__ modep, const float* __restrict__ gwf,
                        float* __restrict__ o) {
    int idx = blockIdx.x * 256 + threadIdx.x;
    int i = idx >> 5, d = idx & 31;
    int mode = *modep;
    int xi = x[i];
    if (xi < 0) xi = 0; if (xi > 100) xi = 100;
    float s = 0.f;
#pragma unroll
    for (int c = 0; c < 32; c++) s += ldf(emb, xi * 32 + c, mode) * gwf[c * 32 + d];
    o[idx] = s;
}

// ---------------- h @ W (layer l) ----------------
__global__ void k_matw(const float* __restrict__ h, const float* __restrict__ gwf, int l, float* __restrict__ o) {
    int idx = blockIdx.x * 256 + threadIdx.x;
    int i = idx >> 5, d = idx & 31;
    const float* W = gwf + l * 1024;
    float s = 0.f;
#pragma unroll
    for (int c = 0; c < 32; c++) s += h[i * 32 + c] * W[c * 32 + d];
    o[idx] = s;
}

// ---------------- An @ hw + b (sparse; eye term separate) ----------------
__global__ void k_agg(const float* __restrict__ hw, const int* __restrict__ row_ptr,
                      const int* __restrict__ col_idx, const float* __restrict__ dinv,
                      const float* __restrict__ gbf, int l, float* __restrict__ o) {
    int idx = blockIdx.x * 256 + threadIdx.x;
    int i = idx >> 5, d = idx & 31;
    int base = row_ptr[i], len = row_ptr[i + 1] - base;
    float di = dinv[i];
    float acc = di * hw[i * 32 + d];  // eye term of Ahat
    for (int t = 0; t < len; t++) {
        int c = col_idx[base + t];
        acc += dinv[c] * hw[c * 32 + d];
    }
    o[idx] = di * acc + gbf[l * 32 + d];
}

// ---------------- graph norm + relu (single block, 1024 threads) ----------------
__global__ void k_norm(const float* __restrict__ in, float* __restrict__ out) {
    __shared__ float red[1024];
    __shared__ float mean[32], rstd[32];
    int t = threadIdx.x, d = t & 31, g = t >> 5;   // 32 groups of 32
    float p = 0.f;
    for (int r = g; r < NN; r += 32) p += in[r * 32 + d];
    red[t] = p;
    __syncthreads();
    if (t < 32) { float s = 0.f; for (int k = 0; k < 32; k++) s += red[k * 32 + t]; mean[t] = s / (float)NN; }
    __syncthreads();
    p = 0.f;
    for (int r = g; r < NN; r += 32) { float v = in[r * 32 + d] - mean[d]; p += v * v; }
    red[t] = p;
    __syncthreads();
    if (t < 32) { float s = 0.f; for (int k = 0; k < 32; k++) s += red[k * 32 + t]; rstd[t] = rsqrtf(s / (float)NN + 1e-5f); }
    __syncthreads();
    for (int e = t; e < NN * 32; e += 1024) {
        int dd = e & 31;
        out[e] = fmaxf((in[e] - mean[dd]) * rstd[dd], 0.f);
    }
}

// ---------------- per-distinct-pair MLP1/MLP2, premultiplied by multiplicity ----------------
__global__ void k_edgemlp(const float* __restrict__ h, const int* __restrict__ row_ptr,
                          const int* __restrict__ col_idx, const int* __restrict__ pr_row,
                          const float* __restrict__ cntv,
                          const float* __restrict__ w1f, const float* __restrict__ b1f,
                          const float* __restrict__ w2f, const float* __restrict__ b2f,
                          float* __restrict__ xep, float* __restrict__ mulp) {
    int t = threadIdx.x, d = t & 31;
    int p = blockIdx.x * 8 + (t >> 5);
    if (p >= NE) return;
    if (p >= row_ptr[NN]) { xep[p * 32 + d] = 0.f; mulp[p * 32 + d] = 0.f; return; }
    int i = pr_row[p], j = col_idx[p];
    float a1 = b1f[d], a2 = b2f[d];
#pragma unroll
    for (int c = 0; c < 32; c++) {
        float hv = h[i * 32 + c];
        a1 += hv * w1f[c * 32 + d];
        a2 += hv * w2f[c * 32 + d];
    }
#pragma unroll
    for (int c = 0; c < 32; c++) {
        float hv = h[j * 32 + c];
        a1 += hv * w1f[(32 + c) * 32 + d];
        a2 += hv * w2f[(32 + c) * 32 + d];
    }
    float cv = cntv[p];
    xep[p * 32 + d]  = cv * fmaxf(a1, 0.f);
    mulp[p * 32 + d] = cv * fmaxf(a2, 0.f);
}

#define DOT4(Z, A, W) Z += A.x * W.x + A.y * W.y + A.z * W.z + A.w * W.w

// ---------------- fused: C gather + z + masked stats; finalize in last block ----------------
__global__ __launch_bounds__(256) void k_big(const int* __restrict__ row_ptr, const int* __restrict__ col_idx,
                                             const int* __restrict__ cell,
                                             const float4* __restrict__ xep4, const float4* __restrict__ mulp4,
                                             const float* __restrict__ w3q,
                                             float* __restrict__ stats, int* __restrict__ done,
                                             float* __restrict__ nrm) {
    __shared__ float ws1[4][32], ws2[4][32], wcm[4];
    __shared__ int amlast;
    int t = threadIdx.x, lane = t & 63, w = t >> 6;
    int n = blockIdx.x * 256 + t;           // one cell per thread; block stays in one row
    int i = n / NN;
    int j = n - i * NN;
    int base = row_ptr[i];
    int len = row_ptr[i + 1] - base;
    float4 a0 = {0.f,0.f,0.f,0.f}, a1 = a0, a2 = a0, a3 = a0, a4 = a0, a5 = a0, a6 = a0, a7 = a0;
    bool hit = false;
    const int* cellcol = cell + j;
    for (int tt = 0; tt < len; tt++) {
        int e1 = base + tt;
        int k = col_idx[e1];
        int e2 = cellcol[k * NN];
        if (e2 >= 0) {
            hit = true;
            const float4* xr = xep4 + e1 * 8;
            const float4* mr = mulp4 + e2 * 8;
            float4 x, m;
            x = xr[0]; m = mr[0]; a0.x += x.x*m.x; a0.y += x.y*m.y; a0.z += x.z*m.z; a0.w += x.w*m.w;
            x = xr[1]; m = mr[1]; a1.x += x.x*m.x; a1.y += x.y*m.y; a1.z += x.z*m.z; a1.w += x.w*m.w;
            x = xr[2]; m = mr[2]; a2.x += x.x*m.x; a2.y += x.y*m.y; a2.z += x.z*m.z; a2.w += x.w*m.w;
            x = xr[3]; m = mr[3]; a3.x += x.x*m.x; a3.y += x.y*m.y; a3.z += x.z*m.z; a3.w += x.w*m.w;
            x = xr[4]; m = mr[4]; a4.x += x.x*m.x; a4.y += x.y*m.y; a4.z += x.z*m.z; a4.w += x.w*m.w;
            x = xr[5]; m = mr[5]; a5.x += x.x*m.x; a5.y += x.y*m.y; a5.z += x.z*m.z; a5.w += x.w*m.w;
            x = xr[6]; m = mr[6]; a6.x += x.x*m.x; a6.y += x.y*m.y; a6.z += x.z*m.z; a6.w += x.w*m.w;
            x = xr[7]; m = mr[7]; a7.x += x.x*m.x; a7.y += x.y*m.y; a7.z += x.z*m.z; a7.w += x.w*m.w;
        }
    }
    bool adj = cell[n] >= 0;
    float af = adj ? 1.f : 0.f;
    float msk = (hit || adj) ? 1.f : 0.f;
    float s1[32], s2[32];
#pragma unroll
    for (int d = 0; d < 32; d++) {
        const float4* wr = (const float4*)(w3q + d * 36);
        float4 wv = wr[8];                  // wv.x = ind weight, wv.y = b3[d]
        float z = wv.y + af * wv.x;
        wv = wr[0]; DOT4(z, a0, wv);
        wv = wr[1]; DOT4(z, a1, wv);
        wv = wr[2]; DOT4(z, a2, wv);
        wv = wr[3]; DOT4(z, a3, wv);
        wv = wr[4]; DOT4(z, a4, wv);
        wv = wr[5]; DOT4(z, a5, wv);
        wv = wr[6]; DOT4(z, a6, wv);
        wv = wr[7]; DOT4(z, a7, wv);
        s1[d] = msk * z;
        s2[d] = msk * z * z;
    }
    // wave butterflies, cross-wave LDS, global atomics
#pragma unroll
    for (int d = 0; d < 32; d++) {
        float v = s1[d];
        for (int off = 32; off >= 1; off >>= 1) v += __shfl_xor(v, off);
        if (lane == 0) ws1[w][d] = v;
        float u = s2[d];
        for (int off = 32; off >= 1; off >>= 1) u += __shfl_xor(u, off);
        if (lane == 0) ws2[w][d] = u;
    }
    {
        float v = msk;
        for (int off = 32; off >= 1; off >>= 1) v += __shfl_xor(v, off);
        if (lane == 0) wcm[w] = v;
    }
    __syncthreads();
    if (t < 32) {
        float a = 0.f, b = 0.f;
        for (int k = 0; k < 4; k++) { a += ws1[k][t]; b += ws2[k][t]; }
        atomicAdd(&stats[t], a);
        atomicAdd(&stats[32 + t], b);
    }
    if (t == 64) atomicAdd(&stats[64], wcm[0] + wcm[1] + wcm[2] + wcm[3]);
    __syncthreads();
    if (t == 0) {
        __threadfence();
        amlast = (atomicAdd(done, 1) == GRID_BIG - 1) ? 1 : 0;
    }
    __syncthreads();
    if (amlast && t < 32) {
        float sum1 = atomicAdd(&stats[t], 0.f);        // atomic read: coherent across XCDs
        float sum2 = atomicAdd(&stats[32 + t], 0.f);
        float cmv  = atomicAdd(&stats[64], 0.f);
        if (cmv < 1.f) cmv = 1.f;
        float mean = sum1 / cmv;
        float var = sum2 / cmv - mean * mean;
        nrm[t] = mean;
        nrm[32 + t] = rsqrtf(fmaxf(var, 0.f) + 1e-5f);
    }
}

// ---------------- output: recompute C at pos pairs (both directions), norm, sym, linear ----------------
__global__ void k_out(const int* __restrict__ pos, const int* __restrict__ row_ptr,
                      const int* __restrict__ col_idx, const int* __restrict__ cell,
                      const float* __restrict__ xep, const float* __restrict__ mulp,
                      const float* __restrict__ h,
                      const float* __restrict__ w3q,
                      const float* __restrict__ nrm,
                      const float* __restrict__ linf, const float* __restrict__ linb,
                      const int* __restrict__ modep, void* __restrict__ outp) {
    __shared__ float Cb[4][2][32];
    int t = threadIdx.x;
    int w = t >> 6, lane = t & 63, d = lane & 31, dir = lane >> 5;
    int p = blockIdx.x * 4 + w;
    int a = pos[2 * p], b = pos[2 * p + 1];
    if ((unsigned)a >= (unsigned)NN) a = 0;
    if ((unsigned)b >= (unsigned)NN) b = 0;
    int r = dir ? b : a;
    int cc = dir ? a : b;
    int base = row_ptr[r], len = row_ptr[r + 1] - base;
    float acc = 0.f;
    bool hit = false;
    for (int tt = 0; tt < len; tt++) {
        int e1 = base + tt;
        int k = col_idx[e1];
        int e2 = cell[k * NN + cc];
        if (e2 >= 0) { hit = true; acc += xep[e1 * 32 + d] * mulp[e2 * 32 + d]; }
    }
    Cb[w][dir][d] = acc;
    bool adj = cell[r * NN + cc] >= 0;
    float msk = (hit || adj) ? 1.f : 0.f;
    __syncthreads();
    float z = w3q[d * 36 + 33] + (adj ? 1.f : 0.f) * w3q[d * 36 + 32];
#pragma unroll
    for (int c = 0; c < 32; c++) z += Cb[w][dir][c] * w3q[d * 36 + c];
    float zn = fmaxf((z - nrm[d]) * nrm[32 + d], 0.f);
    float zp = __shfl_xor(zn, 32);                 // partner direction's zn
    float symd = msk * zn * zp;                    // sym[r,cc,d]
    float xxd = h[a * 32 + d] * h[b * 32 + d];
    float contrib = symd * linf[d] + xxd * linf[32 + d];
    for (int off = 16; off >= 1; off >>= 1) contrib += __shfl_xor(contrib, off);
    if (lane == 0) {
        float v = contrib + linb[0];
        v = fminf(fmaxf(v, -1e4f), 1e4f);          // canary clamp
        if (*modep) ((bf16*)outp)[p] = __float2bfloat16(v);
        else        ((float*)outp)[p] = v;
    }
}

extern "C" void kernel_launch(void* const* d_in, const int* in_sizes, int n_in,
                              void* d_out, int out_size, void* d_ws, size_t ws_size,
                              hipStream_t stream) {
    const void* px  = d_in[0];  const void* pei = d_in[1];  const void* ppos = d_in[2];
    const void* pemb = d_in[3]; const void* pgW = d_in[4];  const void* pgB  = d_in[5];
    const void* pm1W = d_in[6]; const void* pm1B = d_in[7]; const void* pm2W = d_in[8];
    const void* pm2B = d_in[9]; const void* pm3W = d_in[10]; const void* pm3B = d_in[11];
    const void* plW = d_in[12]; const void* plB = d_in[13];
    {   // size-based resolution (identity under dict order; robust to reordering)
        int c2048 = 0, c64 = 0, c32 = 0;
        for (int i = 0; i < n_in; i++) {
            int s = in_sizes[i]; const void* p = d_in[i];
            switch (s) {
                case 768:   px = p; break;
                case 49152: pei = p; break;
                case 8192:  ppos = p; break;
                case 3232:  pemb = p; break;
                case 2048:  if (c2048 == 0) pgW = p; else if (c2048 == 1) pm1W = p; else pm2W = p; c2048++; break;
                case 64:    if (c64 == 0) pgB = p; else plW = p; c64++; break;
                case 32:    if (c32 == 0) pm1B = p; else if (c32 == 1) pm2B = p; else pm3B = p; c32++; break;
                case 1056:  pm3W = p; break;
                case 1:     plB = p; break;
                default: break;
            }
        }
    }

    char* ws = (char*)d_ws;
    size_t off = 0;
    auto alloc = [&](size_t bytes) -> void* {
        void* pp = ws + off;
        off += (bytes + 255) & ~(size_t)255;
        return pp;
    };
    int*   cell    = (int*)alloc(NCELL * 4);       // counts, then pairIdx in-place
    int*   rowlen  = (int*)alloc(NN * 4);
    int*   row_ptr = (int*)alloc((NN + 1) * 4);
    int*   col_idx = (int*)alloc(NE * 4);
    float* cntv    = (float*)alloc(NE * 4);
    int*   pr_row  = (int*)alloc(NE * 4);
    int*   cursor  = (int*)alloc(NN * 4);
    float* dinv    = (float*)alloc(NN * 4);
    float* h       = (float*)alloc(NN * 32 * 4);
    float* bufA    = (float*)alloc(NN * 32 * 4);
    float* bufB    = (float*)alloc(NN * 32 * 4);
    float* xep     = (float*)alloc(NE * 32 * 4);
    float* mulp    = (float*)alloc(NE * 32 * 4);
    float* stats   = (float*)alloc(66 * 4);
    float* nrm     = (float*)alloc(64 * 4);
    float* gwf     = (float*)alloc(2048 * 4);
    float* gbf     = (float*)alloc(64 * 4);
    float* w1f     = (float*)alloc(2048 * 4);
    float* b1f     = (float*)alloc(32 * 4);
    float* w2f     = (float*)alloc(2048 * 4);
    float* b2f     = (float*)alloc(32 * 4);
    float* w3q     = (float*)alloc(32 * 36 * 4);
    float* linf    = (float*)alloc(64 * 4);
    float* linb    = (float*)alloc(4);
    int*   mode    = (int*)alloc(4);
    int*   done    = (int*)alloc(4);

    k_setup<<<GRID_BIG + 2, 256, 0, stream>>>(pgW, pgB, pm1W, pm1B, pm2W, pm2B, pm3W, pm3B, plW, plB,
                                              pemb, cell, stats, cursor, rowlen, done, mode,
                                              gwf, gbf, w1f, b1f, w2f, b2f, w3q, linf, linb);
    k_scatter<<<NE / 256, 256, 0, stream>>>((const int*)pei, cell, rowlen);
    k_scan<<<1, 256, 0, stream>>>(rowlen, row_ptr, dinv);
    k_fillpar<<<GRID_BIG, 256, 0, stream>>>(cell, row_ptr, cursor, col_idx, cntv, pr_row);
    k_matw0<<<NN * 32 / 256, 256, 0, stream>>>((const int*)px, pemb, mode, gwf, bufA);
    k_agg<<<NN * 32 / 256, 256, 0, stream>>>(bufA, row_ptr, col_idx, dinv, gbf, 0, bufB);
    k_norm<<<1, 1024, 0, stream>>>(bufB, h);
    k_matw<<<NN * 32 / 256, 256, 0, stream>>>(h, gwf, 1, bufA);
    k_agg<<<NN * 32 / 256, 256, 0, stream>>>(bufA, row_ptr, col_idx, dinv, gbf, 1, bufB);
    k_norm<<<1, 1024, 0, stream>>>(bufB, h);
    k_edgemlp<<<NE / 8, 256, 0, stream>>>(h, row_ptr, col_idx, pr_row, cntv, w1f, b1f, w2f, b2f, xep, mulp);
    k_big<<<GRID_BIG, 256, 0, stream>>>(row_ptr, col_idx, cell, (const float4*)xep, (const float4*)mulp,
                                        w3q, stats, done, nrm);
    k_out<<<NPOS / 4, 256, 0, stream>>>((const int*)ppos, row_ptr, col_idx, cell, xep, mulp, h,
                                        w3q, nrm, linf, linb, mode, d_out);
}